// Round 18
// baseline (50.794 us; speedup 1.0000x reference)
//
#include <hip/hip_runtime.h>

typedef __attribute__((ext_vector_type(8)))  short short8;
typedef __attribute__((ext_vector_type(16))) float f32x16;

#define B_SZ  16
#define NPTS  4096
#define MBLK  256                   // 4 waves
#define PRB   256                   // pred rows per block (64/wave, 2x32 frags)
#define NFR   2
#define NCH   (NPTS / PRB)          // 16 row-chunks
#define NHALF 4                     // target quarters per (dir,b,chunk)
#define TPB_T (NPTS / NHALF)        // 1024 targets scanned per block
#define STGT  512                   // targets per LDS stage
#define STILE (STGT / 32)           // 16 tiles per stage
#define NSTG  (TPB_T / STGT)        // 2 stages
#define TOT   (2 * B_SZ * NPTS)     // 131072
#define NPT1  (B_SZ * NPTS)         // 65536 points per input array
#define BLK   256

__device__ __forceinline__ unsigned short f2bf(float f) {
    unsigned u = __float_as_uint(f);
    return (unsigned short)((u + 0x7FFFu + ((u >> 16) & 1u)) >> 16);
}
__device__ __forceinline__ float bf2f(unsigned short s) {
    return __uint_as_float(((unsigned)s) << 16);
}
__device__ __forceinline__ short n2(unsigned short s) {
    return (short)f2bf(-2.0f * bf2f(s));
}
// NOTE: no min3f inline-asm. R10/R13/R14 (asm min3 on MFMA results) failed;
// fminf-only rounds (R9/R11/R12/R15/R16/R17) all passed. Never reintroduce.

// ---------------- prep: per-point B-fragment entries, computed ONCE ---------
// plane 0 (idx 0..131071):        e0 = {hx,hy,hz,hx,hy,hz,lx,ly}
// plane 1 (idx 131072..262143):   e1 = {lz,lx,ly,lz,ONE,ONE,s2h,s2l}
// (byte-identical to R17's in-kernel construction; points 0..65535 = pred,
//  65536..131071 = target)
__global__ __launch_bounds__(BLK) void chamfer_prep(
    const float* __restrict__ pred, const float* __restrict__ target,
    short8* __restrict__ prep)
{
    const int id = blockIdx.x * BLK + threadIdx.x;   // 0 .. 131071
    const float* src = (id < NPT1) ? pred : target;
    const int p = id & (NPT1 - 1);
    const float* o = src + (size_t)p * 3;
    const short ONE = (short)0x3F80;
    float x = o[0], y = o[1], z = o[2];
    unsigned short hx = f2bf(x), hy = f2bf(y), hz = f2bf(z);
    unsigned short lx = f2bf(x - bf2f(hx));
    unsigned short ly = f2bf(y - bf2f(hy));
    unsigned short lz = f2bf(z - bf2f(hz));
    float s2 = fmaf(z, z, fmaf(y, y, x * x));
    unsigned short s2h = f2bf(s2), s2l = f2bf(s2 - bf2f(s2h));
    short8 e0, e1;
    e0[0]=(short)hx; e0[1]=(short)hy; e0[2]=(short)hz;
    e0[3]=(short)hx; e0[4]=(short)hy; e0[5]=(short)hz;
    e0[6]=(short)lx; e0[7]=(short)ly;
    e1[0]=(short)lz; e1[1]=(short)lx; e1[2]=(short)ly;
    e1[3]=(short)lz; e1[4]=ONE;       e1[5]=ONE;
    e1[6]=(short)s2h; e1[7]=(short)s2l;
    prep[id]       = e0;
    prep[TOT + id] = e1;
}

// ---------------------------------------------------------------------------
// R17-proven two-pass split-precision chamfer (absmax 0.0). ONE change:
// staging reads ready-made fragments from prep (16B load -> ds_write) instead
// of converting raw floats — each point was being converted 32x per
// direction; now once total (prep). All other paths R17 verbatim.
// ---------------------------------------------------------------------------
__global__ __launch_bounds__(MBLK, 2) void chamfer_mfma(
    const float* __restrict__ pred, const float* __restrict__ target,
    const short8* __restrict__ prep, float* __restrict__ ws)
{
    __shared__ short8   sB[STILE * 64];   // 16 KB B fragments
    __shared__ unsigned rowLds[MBLK];     // slow-path row mins only

    const int dir = blockIdx.y;
    const float* own = dir ? target : pred;

    const int bx    = blockIdx.x;               // [0, 1024)
    const int b     = bx / (NCH * NHALF);       // 64 blocks per batch
    const int chunk = (bx / NHALF) & (NCH - 1);
    const int half  = bx & (NHALF - 1);
    const int tid   = threadIdx.x;
    const int lane  = tid & 63;
    const int w     = tid >> 6;
    const int r32   = lane & 31;
    const int h     = lane >> 5;
    const short ONE = (short)0x3F80;

    // ---- A fragments: 2 x 32 own rows per wave (R17 verbatim) ----
    short8 af[NFR];
    #pragma unroll
    for (int f = 0; f < NFR; ++f) {
        const float* pp = own +
            ((size_t)b*NPTS + chunk*PRB + w*64 + f*32 + r32)*3;
        float x = pp[0], y = pp[1], z = pp[2];
        unsigned short phx=f2bf(x), phy=f2bf(y), phz=f2bf(z);
        unsigned short plx=f2bf(x-bf2f(phx)), ply=f2bf(y-bf2f(phy)),
                       plz=f2bf(z-bf2f(phz));
        short8 v;
        if (h == 0) {
            v[0]=n2(phx); v[1]=n2(phy); v[2]=n2(phz);
            v[3]=n2(plx); v[4]=n2(ply); v[5]=n2(plz);
            v[6]=n2(phx); v[7]=n2(phy);
        } else {
            float p2 = fmaf(z,z,fmaf(y,y,x*x));
            unsigned short p2h=f2bf(p2), p2l=f2bf(p2-bf2f(p2h));
            v[0]=n2(phz); v[1]=n2(plx); v[2]=n2(ply); v[3]=n2(plz);
            v[4]=(short)p2h; v[5]=(short)p2l; v[6]=ONE; v[7]=ONE;
        }
        af[f] = v;
    }

    // ---- layout probe (R17 verbatim) ----
    f32x16 zc;
    #pragma unroll
    for (int r = 0; r < 16; ++r) zc[r] = 0.0f;
    short8 mA = {0,0,0,0,0,0,0,0}, mB = {0,0,0,0,0,0,0,0};
    if (h == 0) { mA[0] = (short)f2bf((float)r32); mB[0] = ONE; }
    f32x16 pr = __builtin_amdgcn_mfma_f32_32x32x16_bf16(mA, mB, zc, 0, 0, 0);
    int lab[16];
    bool ok = true;
    #pragma unroll
    for (int r = 0; r < 16; ++r) {
        lab[r] = ((int)(pr[r] + 0.5f)) & 31;
        ok = ok && (lab[r] == ((r & 3) + 8 * (r >> 2) + 4 * h));
    }
    const bool fast = __all(ok) != 0;

    // ---- scan this block's 1024 targets in 2 staged passes ----
    f32x16 rmin0, rmin1;
    #pragma unroll
    for (int r = 0; r < 16; ++r) { rmin0[r] = 1e30f; rmin1[r] = 1e30f; }

    // opp points in prep: pred plane starts at 0, target at NPT1
    const size_t oppBase = (dir ? 0 : NPT1) + (size_t)b * NPTS + half * TPB_T;

    for (int s = 0; s < NSTG; ++s) {
        __syncthreads();   // previous stage's compute done
        // ---- stage 512 targets: pure 16B copy from prep ----
        #pragma unroll
        for (int i = 0; i < (STILE*64)/MBLK; ++i) {   // 4 entries/thread
            int e  = i * MBLK + tid;
            int t  = e >> 6, l2 = e & 63;
            int cc = l2 & 31, hh = l2 >> 5;
            sB[e] = prep[(size_t)hh * TOT + oppBase + s*STGT + t*32 + cc];
        }
        __syncthreads();

        for (int t = 0; t < STILE; ++t) {
            short8 b0 = sB[t*64 + lane];
            f32x16 a0 = __builtin_amdgcn_mfma_f32_32x32x16_bf16(af[0], b0, zc, 0,0,0);
            f32x16 a1 = __builtin_amdgcn_mfma_f32_32x32x16_bf16(af[1], b0, zc, 0,0,0);
            #pragma unroll
            for (int r = 0; r < 16; ++r) {
                rmin0[r] = fminf(a0[r], rmin0[r]);
                rmin1[r] = fminf(a1[r], rmin1[r]);
            }
        }
    }

    // ---- epilogue (R17 verbatim): per-row shfl fold, write by LABEL ----
    float* wr = ws + (size_t)half * TOT
                   + ((size_t)dir * B_SZ + b) * NPTS + chunk * PRB;
    if (fast) {
        #pragma unroll
        for (int r = 0; r < 16; ++r) {
            float v0 = rmin0[r];
            v0 = fminf(v0, __shfl_xor(v0, 1, 64));
            v0 = fminf(v0, __shfl_xor(v0, 2, 64));
            v0 = fminf(v0, __shfl_xor(v0, 4, 64));
            v0 = fminf(v0, __shfl_xor(v0, 8, 64));
            v0 = fminf(v0, __shfl_xor(v0, 16, 64));
            float v1 = rmin1[r];
            v1 = fminf(v1, __shfl_xor(v1, 1, 64));
            v1 = fminf(v1, __shfl_xor(v1, 2, 64));
            v1 = fminf(v1, __shfl_xor(v1, 4, 64));
            v1 = fminf(v1, __shfl_xor(v1, 8, 64));
            v1 = fminf(v1, __shfl_xor(v1, 16, 64));
            if (r32 == 0) {
                wr[w*64 +  0 + lab[r]] = v0;
                wr[w*64 + 32 + lab[r]] = v1;
            }
        }
    } else {
        rowLds[tid] = 0x7F7F7F7Fu;
        __syncthreads();
        #pragma unroll
        for (int r = 0; r < 16; ++r) {
            atomicMin(&rowLds[w*64 +  0 + lab[r]],
                      __float_as_uint(fmaxf(rmin0[r], 0.0f)));
            atomicMin(&rowLds[w*64 + 32 + lab[r]],
                      __float_as_uint(fmaxf(rmin1[r], 0.0f)));
        }
        __syncthreads();
        wr[tid] = __uint_as_float(rowLds[tid]);
    }
}

// -------- combine: min over the 4 quarters, then mean-reduce -----------------
__global__ __launch_bounds__(BLK) void chamfer_combine(
    const float* __restrict__ ws, float* __restrict__ out)
{
    const int idx = blockIdx.x * BLK + threadIdx.x;   // 0 .. TOT-1
    float v = fminf(fminf(ws[idx],           ws[TOT + idx]),
                    fminf(ws[2*TOT + idx],   ws[3*TOT + idx]));

    for (int off = 32; off > 0; off >>= 1)
        v += __shfl_down(v, off, 64);

    __shared__ float red[4];
    const int tid = threadIdx.x;
    if ((tid & 63) == 0) red[tid >> 6] = v;
    __syncthreads();
    if (tid == 0) {
        float s = (red[0] + red[1]) + (red[2] + red[3]);
        atomicAdd(out, s * (1.0f / ((float)B_SZ * (float)NPTS)));
    }
}

// ---------------- fallback (round-1 kernel) if ws too small ------------------
__global__ __launch_bounds__(BLK) void chamfer_kernel(
    const float* __restrict__ pred, const float* __restrict__ target,
    float* __restrict__ out)
{
    __shared__ float4 sOpp[NPTS];

    const int dir = blockIdx.y;
    const float* own = (dir == 0) ? pred : target;
    const float* opp = (dir == 0) ? target : pred;

    const int b     = blockIdx.x >> 4;
    const int chunk = blockIdx.x & 15;
    const int tid   = threadIdx.x;

    const float* oppB = opp + (size_t)b * NPTS * 3;
    for (int j = tid; j < NPTS; j += BLK) {
        float x = oppB[3 * j + 0];
        float y = oppB[3 * j + 1];
        float z = oppB[3 * j + 2];
        sOpp[j] = make_float4(-2.0f * x, -2.0f * y, -2.0f * z,
                              fmaf(z, z, fmaf(y, y, x * x)));
    }
    __syncthreads();

    const int i = chunk * BLK + tid;
    const float* op = own + ((size_t)b * NPTS + i) * 3;
    const float px = op[0], py = op[1], pz = op[2];
    const float p2 = fmaf(pz, pz, fmaf(py, py, px * px));

    float m0 = 1e30f, m1 = 1e30f, m2 = 1e30f, m3 = 1e30f;
    for (int j = 0; j < NPTS; j += 8) {
        float4 t0 = sOpp[j + 0];
        float4 t1 = sOpp[j + 1];
        float4 t2 = sOpp[j + 2];
        float4 t3 = sOpp[j + 3];
        float4 t4 = sOpp[j + 4];
        float4 t5 = sOpp[j + 5];
        float4 t6 = sOpp[j + 6];
        float4 t7 = sOpp[j + 7];
        m0 = fminf(m0, fmaf(t0.x, px, fmaf(t0.y, py, fmaf(t0.z, pz, t0.w))));
        m1 = fminf(m1, fmaf(t1.x, px, fmaf(t1.y, py, fmaf(t1.z, pz, t1.w))));
        m2 = fminf(m2, fmaf(t2.x, px, fmaf(t2.y, py, fmaf(t2.z, pz, t2.w))));
        m3 = fminf(m3, fmaf(t3.x, px, fmaf(t3.y, py, fmaf(t3.z, pz, t3.w))));
        m0 = fminf(m0, fmaf(t4.x, px, fmaf(t4.y, py, fmaf(t4.z, pz, t4.w))));
        m1 = fminf(m1, fmaf(t5.x, px, fmaf(t5.y, py, fmaf(t5.z, pz, t5.w))));
        m2 = fminf(m2, fmaf(t6.x, px, fmaf(t6.y, py, fmaf(t6.z, pz, t6.w))));
        m3 = fminf(m3, fmaf(t7.x, px, fmaf(t7.y, py, fmaf(t7.z, pz, t7.w))));
    }
    float v = fminf(fminf(m0, m1), fminf(m2, m3)) + p2;

    for (int off = 32; off > 0; off >>= 1)
        v += __shfl_down(v, off, 64);

    __syncthreads();
    float* red = (float*)sOpp;
    if ((tid & 63) == 0) red[tid >> 6] = v;
    __syncthreads();
    if (tid == 0) {
        float s = (red[0] + red[1]) + (red[2] + red[3]);
        atomicAdd(out, s * (1.0f / ((float)B_SZ * (float)NPTS)));
    }
}

extern "C" void kernel_launch(void* const* d_in, const int* in_sizes, int n_in,
                              void* d_out, int out_size, void* d_ws, size_t ws_size,
                              hipStream_t stream) {
    const float* pred   = (const float*)d_in[0];
    const float* target = (const float*)d_in[1];
    float* out = (float*)d_out;

    hipMemsetAsync(out, 0, sizeof(float), stream);

    const size_t prepBytes = (size_t)2 * TOT * sizeof(short8);    // 4 MB
    const size_t rowBytes  = (size_t)NHALF * TOT * sizeof(float); // 2 MB
    if (ws_size >= prepBytes + rowBytes) {
        short8* prep = (short8*)d_ws;
        float*  ws   = (float*)((char*)d_ws + prepBytes);
        chamfer_prep<<<TOT / BLK, BLK, 0, stream>>>(pred, target, prep);
        dim3 grid1(B_SZ * NCH * NHALF, 2);         // 1024 x 2 = 2048 blocks
        chamfer_mfma<<<grid1, MBLK, 0, stream>>>(pred, target, prep, ws);
        chamfer_combine<<<TOT / BLK, BLK, 0, stream>>>(ws, out);
    } else {
        dim3 grid(B_SZ * (NPTS / BLK), 2);
        chamfer_kernel<<<grid, BLK, 0, stream>>>(pred, target, out);
    }
}

// Round 19
// 36.090 us; speedup vs baseline: 1.4074x; 1.4074x over previous
//
#include <hip/hip_runtime.h>

typedef __attribute__((ext_vector_type(8)))  short short8;
typedef __attribute__((ext_vector_type(16))) float f32x16;

#define B_SZ  16
#define NPTS  4096
#define MBLK  512                   // 8 waves per block
#define PRB   256                   // pred rows per block (32 per wave, NFR=1)
#define NCH   (NPTS / PRB)          // 16 row-chunks per (dir,b)
#define STGT  512                   // targets per LDS stage
#define STILE (STGT / 32)           // 16 tiles per stage
#define NSTG  (NPTS / STGT)         // 8 stages = full target scan per block
#define NRT   (B_SZ * NPTS)         // 65536 rows per direction

__device__ __forceinline__ unsigned short f2bf(float f) {
    unsigned u = __float_as_uint(f);
    return (unsigned short)((u + 0x7FFFu + ((u >> 16) & 1u)) >> 16);
}
__device__ __forceinline__ float bf2f(unsigned short s) {
    return __uint_as_float(((unsigned)s) << 16);
}
__device__ __forceinline__ short n2(unsigned short s) {
    return (short)f2bf(-2.0f * bf2f(s));
}
// NOTE: no min3f inline-asm. R10/R13/R14 (asm min3 on MFMA results) failed;
// fminf-only rounds (R9/R11/R12/R15-R18) all passed. Never reintroduce.

// ---------------------------------------------------------------------------
// FUSED single-kernel chamfer. Structure change vs R12 (proven 45.6us,
// absmax 0.0): each block owns 256 complete rows (8 waves x 32 rows) and
// scans ALL 4096 targets in 8 LDS stages -> complete row-mins in-block ->
// block-sum -> ONE atomicAdd. Removes prep/ws/combine dispatches and all
// workspace traffic. Staging math / slot algebra / probe / shfl fold:
// R12-verbatim.
//  slot algebra: s0-2:-2ph·th s3-5:-2pl·th s6-8:-2ph·tl s9-11:-2pl·tl
//                s12,13:p2h,p2l s14,15:t2h,t2l   (exact split-bf16)
// ---------------------------------------------------------------------------
__global__ __launch_bounds__(MBLK, 2) void chamfer_fused(
    const float* __restrict__ pred, const float* __restrict__ target,
    float* __restrict__ out)
{
    __shared__ short8   sB[STILE * 64];   // 16 KB B fragments
    __shared__ unsigned rowOut[PRB];      // 1 KB final row-mins (uint bits)
    __shared__ float    red[MBLK / 64];

    const int dir = blockIdx.y;
    const float* own = dir ? target : pred;
    const float* opp = dir ? pred : target;

    const int b     = blockIdx.x >> 4;          // NCH = 16 chunks per batch
    const int chunk = blockIdx.x & (NCH - 1);
    const int tid   = threadIdx.x;
    const int lane  = tid & 63;
    const int w     = tid >> 6;                 // wave 0..7
    const int r32   = lane & 31;
    const int h     = lane >> 5;
    const short ONE = (short)0x3F80;

    // ---- A fragment: this wave's 32 own rows (R12-verbatim math) ----
    short8 af;
    {
        const float* pp = own +
            ((size_t)b*NPTS + chunk*PRB + w*32 + r32)*3;
        float x = pp[0], y = pp[1], z = pp[2];
        unsigned short phx=f2bf(x), phy=f2bf(y), phz=f2bf(z);
        unsigned short plx=f2bf(x-bf2f(phx)), ply=f2bf(y-bf2f(phy)),
                       plz=f2bf(z-bf2f(phz));
        short8 v;
        if (h == 0) {
            v[0]=n2(phx); v[1]=n2(phy); v[2]=n2(phz);
            v[3]=n2(plx); v[4]=n2(ply); v[5]=n2(plz);
            v[6]=n2(phx); v[7]=n2(phy);
        } else {
            float p2 = fmaf(z,z,fmaf(y,y,x*x));
            unsigned short p2h=f2bf(p2), p2l=f2bf(p2-bf2f(p2h));
            v[0]=n2(phz); v[1]=n2(plx); v[2]=n2(ply); v[3]=n2(plz);
            v[4]=(short)p2h; v[5]=(short)p2l; v[6]=ONE; v[7]=ONE;
        }
        af = v;
    }

    // ---- layout probe (R12-verbatim) ----
    f32x16 zc;
    #pragma unroll
    for (int r = 0; r < 16; ++r) zc[r] = 0.0f;
    short8 mA = {0,0,0,0,0,0,0,0}, mB = {0,0,0,0,0,0,0,0};
    if (h == 0) { mA[0] = (short)f2bf((float)r32); mB[0] = ONE; }
    f32x16 pr = __builtin_amdgcn_mfma_f32_32x32x16_bf16(mA, mB, zc, 0, 0, 0);
    int lab[16];
    bool ok = true;
    #pragma unroll
    for (int r = 0; r < 16; ++r) {
        lab[r] = ((int)(pr[r] + 0.5f)) & 31;
        ok = ok && (lab[r] == ((r & 3) + 8 * (r >> 2) + 4 * h));
    }
    const bool fast = __all(ok) != 0;

    if (!fast) rowOut[tid & (PRB - 1)] = 0x7F7F7F7Fu;  // slow-path sentinel

    // ---- scan ALL 4096 targets in 8 staged passes ----
    f32x16 rmin;
    #pragma unroll
    for (int r = 0; r < 16; ++r) rmin[r] = 1e30f;

    const float* oppB = opp + (size_t)b * NPTS * 3;

    for (int s = 0; s < NSTG; ++s) {
        __syncthreads();   // previous stage's compute done
        // ---- stage 512 targets as B fragments (R12-verbatim math) ----
        #pragma unroll
        for (int i = 0; i < (STILE*64)/MBLK; ++i) {   // 2 entries/thread
            int e  = i * MBLK + tid;
            int t  = e >> 6, l2 = e & 63;
            int cc = l2 & 31, hh = l2 >> 5;
            const float* o = oppB + (size_t)(s*STGT + t*32 + cc)*3;
            float tx=o[0], ty=o[1], tz=o[2];
            unsigned short hx=f2bf(tx), hy=f2bf(ty), hz=f2bf(tz);
            unsigned short lx=f2bf(tx-bf2f(hx)), ly=f2bf(ty-bf2f(hy)),
                           lz=f2bf(tz-bf2f(hz));
            short8 v;
            if (hh == 0) {
                v[0]=(short)hx; v[1]=(short)hy; v[2]=(short)hz;
                v[3]=(short)hx; v[4]=(short)hy; v[5]=(short)hz;
                v[6]=(short)lx; v[7]=(short)ly;
            } else {
                float t2 = fmaf(tz,tz,fmaf(ty,ty,tx*tx));
                unsigned short t2h=f2bf(t2), t2l=f2bf(t2-bf2f(t2h));
                v[0]=(short)lz; v[1]=(short)lx; v[2]=(short)ly;
                v[3]=(short)lz; v[4]=ONE; v[5]=ONE;
                v[6]=(short)t2h; v[7]=(short)t2l;
            }
            sB[e] = v;   // contiguous 16B/thread
        }
        __syncthreads();

        for (int t = 0; t < STILE; ++t) {
            short8 b0 = sB[t*64 + lane];
            f32x16 a0 = __builtin_amdgcn_mfma_f32_32x32x16_bf16(af, b0, zc, 0,0,0);
            #pragma unroll
            for (int r = 0; r < 16; ++r)
                rmin[r] = fminf(a0[r], rmin[r]);
        }
    }

    // ---- row epilogue: shfl fold over 32 cols, COMPLETE mins -> rowOut ----
    __syncthreads();   // also orders slow-path sentinel init
    if (fast) {
        #pragma unroll
        for (int r = 0; r < 16; ++r) {
            float v0 = rmin[r];
            v0 = fminf(v0, __shfl_xor(v0, 1, 64));
            v0 = fminf(v0, __shfl_xor(v0, 2, 64));
            v0 = fminf(v0, __shfl_xor(v0, 4, 64));
            v0 = fminf(v0, __shfl_xor(v0, 8, 64));
            v0 = fminf(v0, __shfl_xor(v0, 16, 64));
            if (r32 == 0)   // lanes 0 and 32: 16 rows each, disjoint labels
                rowOut[w*32 + lab[r]] = __float_as_uint(v0);
        }
    } else {
        #pragma unroll
        for (int r = 0; r < 16; ++r)
            atomicMin(&rowOut[w*32 + lab[r]],
                      __float_as_uint(fmaxf(rmin[r], 0.0f)));
    }
    __syncthreads();

    // ---- block sum of the 256 complete row-mins -> one atomicAdd ----
    float v = (tid < PRB) ? __uint_as_float(rowOut[tid]) : 0.0f;
    for (int off = 32; off > 0; off >>= 1)
        v += __shfl_down(v, off, 64);
    if ((tid & 63) == 0) red[w] = v;
    __syncthreads();
    if (tid == 0) {
        float s = 0.0f;
        #pragma unroll
        for (int i = 0; i < MBLK / 64; ++i) s += red[i];
        atomicAdd(out, s * (1.0f / (float)NRT));
    }
}

extern "C" void kernel_launch(void* const* d_in, const int* in_sizes, int n_in,
                              void* d_out, int out_size, void* d_ws, size_t ws_size,
                              hipStream_t stream) {
    const float* pred   = (const float*)d_in[0];
    const float* target = (const float*)d_in[1];
    float* out = (float*)d_out;

    hipMemsetAsync(out, 0, sizeof(float), stream);

    // grid: 16 batches x 16 chunks = 256 ; y = 2 directions ; 512 blocks
    dim3 grid(B_SZ * NCH, 2);
    chamfer_fused<<<grid, MBLK, 0, stream>>>(pred, target, out);
}

// Round 20
// 34.040 us; speedup vs baseline: 1.4922x; 1.0602x over previous
//
#include <hip/hip_runtime.h>

typedef __attribute__((ext_vector_type(8)))  short short8;
typedef __attribute__((ext_vector_type(16))) float f32x16;

#define B_SZ  16
#define NPTS  4096
#define MBLK  512                   // 8 waves per block
#define PRB   256                   // pred rows per block (32 per wave)
#define NCH   (NPTS / PRB)          // 16 row-chunks per (dir,b)
#define STGT  1024                  // targets per LDS stage   [R19: 512]
#define STILE (STGT / 32)           // 32 tiles per stage
#define NSTG  (NPTS / STGT)         // 4 stages (8 barriers vs R19's 16)
#define PPT   (STGT / MBLK)         // 2 points per thread per stage
#define NRT   (B_SZ * NPTS)         // 65536 rows per direction

__device__ __forceinline__ unsigned short f2bf(float f) {
    unsigned u = __float_as_uint(f);
    return (unsigned short)((u + 0x7FFFu + ((u >> 16) & 1u)) >> 16);
}
__device__ __forceinline__ float bf2f(unsigned short s) {
    return __uint_as_float(((unsigned)s) << 16);
}
__device__ __forceinline__ short n2(unsigned short s) {
    return (short)f2bf(-2.0f * bf2f(s));
}
// NOTE: no min3f inline-asm. R10/R13/R14 (asm min3 on MFMA results) failed;
// fminf-only rounds (R9/R11/R12/R15-R19) all passed. Never reintroduce.

// ---------------------------------------------------------------------------
// Fused single-kernel chamfer (R19-proven, 36.1us, absmax 0.0). Schedule
// changes only — staging MATH and all reduction paths verbatim:
//  (1) STGT 512->1024: barriers 16->8, 32 tiles of compute per stage
//  (2) T14 issue-early: next stage's raw loads issue BEFORE this stage's
//      compute, hiding global latency under MFMA+fmin
//  (3) dedupe: one thread builds BOTH entries of its point (R19 loaded and
//      converted each point twice per stage)
//  slot algebra: s0-2:-2ph·th s3-5:-2pl·th s6-8:-2ph·tl s9-11:-2pl·tl
//                s12,13:p2h,p2l s14,15:t2h,t2l   (exact split-bf16)
// ---------------------------------------------------------------------------
__global__ __launch_bounds__(MBLK, 2) void chamfer_fused(
    const float* __restrict__ pred, const float* __restrict__ target,
    float* __restrict__ out)
{
    __shared__ short8   sB[STILE * 64];   // 32 KB B fragments
    __shared__ unsigned rowOut[PRB];      // 1 KB final row-mins (uint bits)
    __shared__ float    red[MBLK / 64];

    const int dir = blockIdx.y;
    const float* own = dir ? target : pred;
    const float* opp = dir ? pred : target;

    const int b     = blockIdx.x >> 4;          // NCH = 16 chunks per batch
    const int chunk = blockIdx.x & (NCH - 1);
    const int tid   = threadIdx.x;
    const int lane  = tid & 63;
    const int w     = tid >> 6;                 // wave 0..7
    const int r32   = lane & 31;
    const int h     = lane >> 5;
    const short ONE = (short)0x3F80;

    // ---- A fragment: this wave's 32 own rows (R19 verbatim) ----
    short8 af;
    {
        const float* pp = own +
            ((size_t)b*NPTS + chunk*PRB + w*32 + r32)*3;
        float x = pp[0], y = pp[1], z = pp[2];
        unsigned short phx=f2bf(x), phy=f2bf(y), phz=f2bf(z);
        unsigned short plx=f2bf(x-bf2f(phx)), ply=f2bf(y-bf2f(phy)),
                       plz=f2bf(z-bf2f(phz));
        short8 v;
        if (h == 0) {
            v[0]=n2(phx); v[1]=n2(phy); v[2]=n2(phz);
            v[3]=n2(plx); v[4]=n2(ply); v[5]=n2(plz);
            v[6]=n2(phx); v[7]=n2(phy);
        } else {
            float p2 = fmaf(z,z,fmaf(y,y,x*x));
            unsigned short p2h=f2bf(p2), p2l=f2bf(p2-bf2f(p2h));
            v[0]=n2(phz); v[1]=n2(plx); v[2]=n2(ply); v[3]=n2(plz);
            v[4]=(short)p2h; v[5]=(short)p2l; v[6]=ONE; v[7]=ONE;
        }
        af = v;
    }

    // ---- layout probe (R19 verbatim) ----
    f32x16 zc;
    #pragma unroll
    for (int r = 0; r < 16; ++r) zc[r] = 0.0f;
    short8 mA = {0,0,0,0,0,0,0,0}, mB = {0,0,0,0,0,0,0,0};
    if (h == 0) { mA[0] = (short)f2bf((float)r32); mB[0] = ONE; }
    f32x16 pr = __builtin_amdgcn_mfma_f32_32x32x16_bf16(mA, mB, zc, 0, 0, 0);
    int lab[16];
    bool ok = true;
    #pragma unroll
    for (int r = 0; r < 16; ++r) {
        lab[r] = ((int)(pr[r] + 0.5f)) & 31;
        ok = ok && (lab[r] == ((r & 3) + 8 * (r >> 2) + 4 * h));
    }
    const bool fast = __all(ok) != 0;

    if (!fast) rowOut[tid & (PRB - 1)] = 0x7F7F7F7Fu;  // slow-path sentinel

    // ---- scan ALL 4096 targets in 4 staged passes, T14 issue-early ----
    f32x16 rmin;
    #pragma unroll
    for (int r = 0; r < 16; ++r) rmin[r] = 1e30f;

    const float* oppB = opp + (size_t)b * NPTS * 3;

    // prologue: raw loads for stage 0 (2 points per thread)
    float rx[PPT], ry[PPT], rz[PPT];
    #pragma unroll
    for (int j = 0; j < PPT; ++j) {
        const float* o = oppB + (size_t)(j * MBLK + tid) * 3;
        rx[j] = o[0]; ry[j] = o[1]; rz[j] = o[2];
    }

    for (int s = 0; s < NSTG; ++s) {
        __syncthreads();   // previous stage's compute done (sB free)
        // ---- convert raw -> BOTH fragment entries per point (R19 math) ----
        #pragma unroll
        for (int j = 0; j < PPT; ++j) {
            int p  = j * MBLK + tid;     // point within stage, 0..1023
            int t  = p >> 5, cc = p & 31;
            float tx = rx[j], ty = ry[j], tz = rz[j];
            unsigned short hx=f2bf(tx), hy=f2bf(ty), hz=f2bf(tz);
            unsigned short lx=f2bf(tx-bf2f(hx)), ly=f2bf(ty-bf2f(hy)),
                           lz=f2bf(tz-bf2f(hz));
            float t2 = fmaf(tz,tz,fmaf(ty,ty,tx*tx));
            unsigned short t2h=f2bf(t2), t2l=f2bf(t2-bf2f(t2h));
            short8 v0, v1;
            v0[0]=(short)hx; v0[1]=(short)hy; v0[2]=(short)hz;
            v0[3]=(short)hx; v0[4]=(short)hy; v0[5]=(short)hz;
            v0[6]=(short)lx; v0[7]=(short)ly;
            v1[0]=(short)lz; v1[1]=(short)lx; v1[2]=(short)ly;
            v1[3]=(short)lz; v1[4]=ONE; v1[5]=ONE;
            v1[6]=(short)t2h; v1[7]=(short)t2l;
            sB[t*64 + cc]      = v0;   // hh=0 half of tile t
            sB[t*64 + 32 + cc] = v1;   // hh=1 half of tile t
        }
        __syncthreads();

        // ---- T14: issue NEXT stage's raw loads before compute ----
        if (s + 1 < NSTG) {
            #pragma unroll
            for (int j = 0; j < PPT; ++j) {
                const float* o = oppB +
                    (size_t)((s + 1) * STGT + j * MBLK + tid) * 3;
                rx[j] = o[0]; ry[j] = o[1]; rz[j] = o[2];
            }
        }

        // ---- 32 tiles: ds_read + MFMA + fmin fold (R19 verbatim) ----
        for (int t = 0; t < STILE; ++t) {
            short8 b0 = sB[t*64 + lane];
            f32x16 a0 = __builtin_amdgcn_mfma_f32_32x32x16_bf16(af, b0, zc, 0,0,0);
            #pragma unroll
            for (int r = 0; r < 16; ++r)
                rmin[r] = fminf(a0[r], rmin[r]);
        }
    }

    // ---- row epilogue (R19 verbatim): shfl fold -> complete mins ----
    __syncthreads();   // also orders slow-path sentinel init
    if (fast) {
        #pragma unroll
        for (int r = 0; r < 16; ++r) {
            float v0 = rmin[r];
            v0 = fminf(v0, __shfl_xor(v0, 1, 64));
            v0 = fminf(v0, __shfl_xor(v0, 2, 64));
            v0 = fminf(v0, __shfl_xor(v0, 4, 64));
            v0 = fminf(v0, __shfl_xor(v0, 8, 64));
            v0 = fminf(v0, __shfl_xor(v0, 16, 64));
            if (r32 == 0)   // lanes 0 and 32: 16 rows each, disjoint labels
                rowOut[w*32 + lab[r]] = __float_as_uint(v0);
        }
    } else {
        #pragma unroll
        for (int r = 0; r < 16; ++r)
            atomicMin(&rowOut[w*32 + lab[r]],
                      __float_as_uint(fmaxf(rmin[r], 0.0f)));
    }
    __syncthreads();

    // ---- block sum of the 256 complete row-mins -> one atomicAdd ----
    float v = (tid < PRB) ? __uint_as_float(rowOut[tid]) : 0.0f;
    for (int off = 32; off > 0; off >>= 1)
        v += __shfl_down(v, off, 64);
    if ((tid & 63) == 0) red[w] = v;
    __syncthreads();
    if (tid == 0) {
        float s = 0.0f;
        #pragma unroll
        for (int i = 0; i < MBLK / 64; ++i) s += red[i];
        atomicAdd(out, s * (1.0f / (float)NRT));
    }
}

extern "C" void kernel_launch(void* const* d_in, const int* in_sizes, int n_in,
                              void* d_out, int out_size, void* d_ws, size_t ws_size,
                              hipStream_t stream) {
    const float* pred   = (const float*)d_in[0];
    const float* target = (const float*)d_in[1];
    float* out = (float*)d_out;

    hipMemsetAsync(out, 0, sizeof(float), stream);

    // grid: 16 batches x 16 chunks = 256 ; y = 2 directions ; 512 blocks
    dim3 grid(B_SZ * NCH, 2);
    chamfer_fused<<<grid, MBLK, 0, stream>>>(pred, target, out);
}